// Round 1
// baseline (1064.502 us; speedup 1.0000x reference)
//
#include <hip/hip_runtime.h>
#include <stdint.h>

// ---- problem constants -----------------------------------------------------
// B=32768, D=2048, L=64, SOM 8x8=64 codes. All inputs fp32.
// d_out layout (fp32 elements), in reference return order:
//   x_e[B,D], x_q[B,D], z_e[B,64], z_q[B,64], z_q_neighbors[B,5,64], k[B], z_dist[B,64]
constexpr size_t OFF_XQ = (size_t)32768 * 2048;           //  67108864
constexpr size_t OFF_ZE = OFF_XQ * 2;                     // 134217728
constexpr size_t OFF_ZQ = OFF_ZE + (size_t)32768 * 64;    // 136314880
constexpr size_t OFF_NB = OFF_ZQ + (size_t)32768 * 64;    // 138412032
constexpr size_t OFF_K  = OFF_NB + (size_t)32768 * 5 * 64;// 148897792
constexpr size_t OFF_ZD = OFF_K + 32768;                  // 148930560

typedef __attribute__((ext_vector_type(8))) short short8;
typedef __attribute__((ext_vector_type(4))) float f32x4;
typedef __attribute__((ext_vector_type(4))) unsigned short us4;

__device__ __forceinline__ unsigned short f2bf(float f) {
  unsigned int u = __float_as_uint(f);
  u += 0x7fffu + ((u >> 16) & 1u);        // round-to-nearest-even
  return (unsigned short)(u >> 16);
}

__device__ __forceinline__ float pick4(float4 v, int c) {
  float r = v.x;
  r = (c == 1) ? v.y : r;
  r = (c == 2) ? v.z : r;
  r = (c == 3) ? v.w : r;
  return r;
}

// ---- kernel 0: transpose+convert W_dec_{e,q} [64,2048] -> WT bf16 [2048,64] -
__global__ __launch_bounds__(256) void somvae_wprep(
    const float* __restrict__ We, const float* __restrict__ Wq,
    unsigned short* __restrict__ wt)
{
  const int sel = blockIdx.y;
  const float* W = sel ? Wq : We;
  unsigned short* WT = wt + (size_t)sel * (64 * 2048);
  const int d0 = blockIdx.x * 64;
  __shared__ unsigned short tl[64][68];   // [dd][l] bf16, stride 68 for 8B-aligned reads
  const int t = threadIdx.x;
  for (int i = 4 * t; i < 4096; i += 1024) {
    int l = i >> 6, dd = i & 63;
    float4 v = *(const float4*)(W + (size_t)l * 2048 + d0 + dd);
    tl[dd + 0][l] = f2bf(v.x);
    tl[dd + 1][l] = f2bf(v.y);
    tl[dd + 2][l] = f2bf(v.z);
    tl[dd + 3][l] = f2bf(v.w);
  }
  __syncthreads();
  {
    int dd = t >> 2, c4 = (t & 3) * 16;
    #pragma unroll
    for (int q = 0; q < 4; ++q) {
      us4 v;
      v.x = tl[dd][c4 + 4 * q + 0];
      v.y = tl[dd][c4 + 4 * q + 1];
      v.z = tl[dd][c4 + 4 * q + 2];
      v.w = tl[dd][c4 + 4 * q + 3];
      *(us4*)(WT + (size_t)(d0 + dd) * 64 + c4 + 4 * q) = v;
    }
  }
}

// ---- kernel 1: encoder GEMM (fp32) + SOM distances/argmin/gather -----------
// grid 512 blocks x 256 thr; each block: 64 rows.
__global__ __launch_bounds__(256, 2) void somvae_encoder(
    const float* __restrict__ x, const float* __restrict__ W_enc,
    const float* __restrict__ b_enc, const float* __restrict__ emb,
    float* __restrict__ out)
{
  __shared__ float xsT[64][68];    // [k][r] (transposed x tile); reused as zs[r][j]
  __shared__ float ws[64][68];     // [k][j] W_enc tile
  __shared__ float Erow[64][68];   // [code][j]
  __shared__ double eeD[64];       // |e_c|^2 in fp64

  const int t   = threadIdx.x;
  const int tx  = t & 15;          // output col group j0 = 4*tx
  const int ty  = t >> 4;          // output row group r0 = 4*ty
  const int row0 = blockIdx.x * 64;

  // stage embeddings (64x64) once
  for (int i = 4 * t; i < 4096; i += 1024) {
    float4 v = *(const float4*)(emb + i);
    int c = i >> 6, j = i & 63;
    *(float4*)&Erow[c][j] = v;
  }
  __syncthreads();
  if (t < 64) {
    double s = 0.0;
    #pragma unroll
    for (int j = 0; j < 64; ++j) { double v = (double)Erow[t][j]; s += v * v; }
    eeD[t] = s;
  }

  float acc[4][4] = {};
  for (int kb = 0; kb < 2048; kb += 64) {
    __syncthreads();
    {
      const int m = t & 15, r = t >> 4;
      #pragma unroll
      for (int p = 0; p < 4; ++p) {
        const int rr = r + p * 16;
        float4 v = *(const float4*)(x + (size_t)(row0 + rr) * 2048 + kb + m * 4);
        #pragma unroll
        for (int c0 = 0; c0 < 4; ++c0) {     // rotated to cut bank conflicts
          int c = (c0 + m) & 3;
          xsT[m * 4 + c][rr] = pick4(v, c);
        }
        float4 wv = *(const float4*)(W_enc + (size_t)(kb + rr) * 64 + m * 4);
        *(float4*)&ws[rr][m * 4] = wv;
      }
    }
    __syncthreads();
    #pragma unroll 8
    for (int k = 0; k < 64; ++k) {
      float4 a = *(const float4*)&xsT[k][ty * 4];
      float4 b = *(const float4*)&ws[k][tx * 4];
      float av[4] = {a.x, a.y, a.z, a.w};
      float bv[4] = {b.x, b.y, b.z, b.w};
      #pragma unroll
      for (int i = 0; i < 4; ++i)
        #pragma unroll
        for (int j = 0; j < 4; ++j)
          acc[i][j] = fmaf(av[i], bv[j], acc[i][j]);
    }
  }

  __syncthreads();                 // done reading xsT; reuse it as zs
  float (*zs)[68] = xsT;
  {
    float4 be = *(const float4*)(b_enc + tx * 4);
    float bb[4] = {be.x, be.y, be.z, be.w};
    #pragma unroll
    for (int i = 0; i < 4; ++i) {
      const int r = ty * 4 + i;
      float4 v = make_float4(acc[i][0] + bb[0], acc[i][1] + bb[1],
                             acc[i][2] + bb[2], acc[i][3] + bb[3]);
      *(float4*)(out + OFF_ZE + (size_t)(row0 + r) * 64 + tx * 4) = v;
      *(float4*)&zs[r][tx * 4] = v;
    }
  }
  __syncthreads();

  // phase 2: per-wave (64 lanes = 64 codes / 64 latent dims), 16 rows per wave
  {
    const int lane = t & 63;
    const int rbase = (t >> 6) * 16;
    for (int rr = 0; rr < 16; ++rr) {
      const int r = rbase + rr;
      float dotf = 0.f, sf = 0.f;
      #pragma unroll
      for (int j4 = 0; j4 < 64; j4 += 4) {
        float4 z4 = *(const float4*)&zs[r][j4];      // broadcast
        float4 e4 = *(const float4*)&Erow[lane][j4];
        dotf = fmaf(z4.x, e4.x, dotf); dotf = fmaf(z4.y, e4.y, dotf);
        dotf = fmaf(z4.z, e4.z, dotf); dotf = fmaf(z4.w, e4.w, dotf);
        sf = fmaf(z4.x, z4.x, sf); sf = fmaf(z4.y, z4.y, sf);
        sf = fmaf(z4.z, z4.z, sf); sf = fmaf(z4.w, z4.w, sf);
      }
      // sf is per-row constant across lanes => cannot affect argmin ordering;
      // combine in fp64 so ordering noise is ~1e-16 * |d|.
      double d = (double)sf - 2.0 * (double)dotf + eeD[lane];
      double bd = d; int bi = lane;
      #pragma unroll
      for (int off = 32; off; off >>= 1) {
        double od = __shfl_xor(bd, off, 64);
        int    oi = __shfl_xor(bi, off, 64);
        if (od < bd || (od == bd && oi < bi)) { bd = od; bi = oi; }
      }
      const int k  = bi;           // first index of min (tie-low), all lanes agree
      const int k1 = k >> 3, k2 = k & 7;
      const size_t row = (size_t)(row0 + r);
      const int kup = (k1 < 7) ? k + 8 : k;
      const int kdn = (k1 > 0) ? k - 8 : k;
      const int klf = (k2 > 0) ? k - 1 : k;
      float zq = Erow[k][lane];
      out[OFF_ZQ + row * 64 + lane] = zq;
      const size_t nb = OFF_NB + row * 320;
      out[nb +   0 + lane] = zq;
      out[nb +  64 + lane] = (k1 < 7) ? Erow[kup][lane] : 0.f;
      out[nb + 128 + lane] = (k1 > 0) ? Erow[kdn][lane] : 0.f;
      out[nb + 192 + lane] = 0.f;                         // faithful `==` bug: right = 0
      out[nb + 256 + lane] = (k2 > 0) ? Erow[klf][lane] : 0.f;
      out[OFF_ZD + row * 64 + lane] = (float)d;
      if (lane == 0) out[OFF_K + row] = (float)k;
    }
  }
}

// ---- kernel 2: decoders x_e = z_e@W_dec_e + b, x_q = z_q@W_dec_q + b -------
// bf16 MFMA 16x16x32, K=64 (2 mfma). No LDS, no barriers. grid (512, 2).
__global__ __launch_bounds__(256) void somvae_decoder(
    const float* __restrict__ Wq, const float* __restrict__ bq,
    const float* __restrict__ We, const float* __restrict__ be,
    const unsigned short* __restrict__ wt, int use_wt,
    float* __restrict__ out)
{
  const int sel = blockIdx.y;                  // 0: x_e, 1: x_q
  const float* bias = sel ? bq : be;
  const float* Wf   = sel ? Wq : We;           // fallback path, fp32 [64][2048]
  const unsigned short* WT = wt + (size_t)sel * (64 * 2048); // bf16 [2048][64]
  const float* z = out + (sel ? OFF_ZQ : OFF_ZE);
  float* xo = out + (sel ? OFF_XQ : (size_t)0);
  const int row0 = blockIdx.x * 64;

  const int t = threadIdx.x;
  const int lane = t & 63, w = t >> 6;
  const int m = lane & 15, quad = lane >> 4;

  // A fragments (per-wave 16 rows), loaded once: A[m=lane&15][k=quad*8+j]
  short8 a0, a1;
  {
    const float* zp = z + (size_t)(row0 + 16 * w + m) * 64 + quad * 8;
    float4 u0 = *(const float4*)(zp);
    float4 u1 = *(const float4*)(zp + 4);
    float4 u2 = *(const float4*)(zp + 32);
    float4 u3 = *(const float4*)(zp + 36);
    a0[0]=(short)f2bf(u0.x); a0[1]=(short)f2bf(u0.y); a0[2]=(short)f2bf(u0.z); a0[3]=(short)f2bf(u0.w);
    a0[4]=(short)f2bf(u1.x); a0[5]=(short)f2bf(u1.y); a0[6]=(short)f2bf(u1.z); a0[7]=(short)f2bf(u1.w);
    a1[0]=(short)f2bf(u2.x); a1[1]=(short)f2bf(u2.y); a1[2]=(short)f2bf(u2.z); a1[3]=(short)f2bf(u2.w);
    a1[4]=(short)f2bf(u3.x); a1[5]=(short)f2bf(u3.y); a1[6]=(short)f2bf(u3.z); a1[7]=(short)f2bf(u3.w);
  }

  for (int ct = 0; ct < 32; ++ct) {
    const int d0 = ct * 64;
    #pragma unroll
    for (int c = 0; c < 4; ++c) {
      const int d = d0 + 16 * c + m;
      short8 b0, b1;
      if (use_wt) {
        const unsigned short* wp = WT + (size_t)d * 64;
        b0 = *(const short8*)(wp + quad * 8);
        b1 = *(const short8*)(wp + 32 + quad * 8);
      } else {
        #pragma unroll
        for (int j = 0; j < 8; ++j) {
          b0[j] = (short)f2bf(Wf[(size_t)(quad * 8 + j) * 2048 + d]);
          b1[j] = (short)f2bf(Wf[(size_t)(32 + quad * 8 + j) * 2048 + d]);
        }
      }
      f32x4 acc = {0.f, 0.f, 0.f, 0.f};
      acc = __builtin_amdgcn_mfma_f32_16x16x32_bf16(a0, b0, acc, 0, 0, 0);
      acc = __builtin_amdgcn_mfma_f32_16x16x32_bf16(a1, b1, acc, 0, 0, 0);
      const float bv = bias[d];
      // C/D: col = lane&15 (=m), row = quad*4 + reg
      float* op = xo + (size_t)(row0 + 16 * w + quad * 4) * 2048 + d;
      op[0]        = acc[0] + bv;
      op[2048]     = acc[1] + bv;
      op[2 * 2048] = acc[2] + bv;
      op[3 * 2048] = acc[3] + bv;
    }
  }
}

extern "C" void kernel_launch(void* const* d_in, const int* in_sizes, int n_in,
                              void* d_out, int out_size, void* d_ws, size_t ws_size,
                              hipStream_t stream) {
  (void)in_sizes; (void)n_in; (void)out_size;
  const float* x       = (const float*)d_in[0];
  const float* W_enc   = (const float*)d_in[1];
  const float* b_enc   = (const float*)d_in[2];
  const float* W_dec_q = (const float*)d_in[3];
  const float* b_dec_q = (const float*)d_in[4];
  const float* W_dec_e = (const float*)d_in[5];
  const float* b_dec_e = (const float*)d_in[6];
  const float* emb     = (const float*)d_in[7];
  float* out = (float*)d_out;
  unsigned short* wt = (unsigned short*)d_ws;
  const int use_wt = (ws_size >= (size_t)2 * 64 * 2048 * sizeof(unsigned short)) ? 1 : 0;

  if (use_wt)
    somvae_wprep<<<dim3(32, 2), 256, 0, stream>>>(W_dec_e, W_dec_q, wt);
  somvae_encoder<<<dim3(512), 256, 0, stream>>>(x, W_enc, b_enc, emb, out);
  somvae_decoder<<<dim3(512, 2), 256, 0, stream>>>(W_dec_q, b_dec_q, W_dec_e, b_dec_e,
                                                   wt, use_wt, out);
}